// Round 10
// baseline (238.306 us; speedup 1.0000x reference)
//
#include <hip/hip_runtime.h>
#include <cstdint>
#include <cstddef>

// Problem constants
#define NB 2
#define TT 1024
#define MMEM 1024
#define SS 2048   // M + T
#define FF 1024
#define NHD 16    // heads
#define HD 64     // head dim

typedef __attribute__((ext_vector_type(8))) short bf16x8;
typedef __attribute__((ext_vector_type(4))) float f32x4;

__device__ __forceinline__ float bf2f(short s){
  unsigned u = ((unsigned)(unsigned short)s) << 16;
  float f; __builtin_memcpy(&f, &u, 4); return f;
}
__device__ __forceinline__ short f2bf(float f){
  unsigned u; __builtin_memcpy(&u, &f, 4);
  u += 0x7fffu + ((u >> 16) & 1u);   // RNE
  return (short)(u >> 16);
}

// async global->LDS, 16 B per lane; LDS dest = wave-uniform base + lane*16
typedef const __attribute__((address_space(1))) void gv_t;
typedef __attribute__((address_space(3))) void lv_t;
__device__ __forceinline__ void stage16(const void* g, void* l){
  __builtin_amdgcn_global_load_lds((gv_t*)g, (lv_t*)l, 16, 0, 0);
}

// ---------------- pack / cast kernels ----------------

// fused: kv_bf = bf16(concat(memory, x)) [B*SS,FF]; rel_bf = bf16(rel) [SS,FF]
__global__ void build_inputs(const float* __restrict__ mem, const float* __restrict__ x,
                             const float* __restrict__ rel,
                             short* __restrict__ kv, short* __restrict__ relo){
  int i = blockIdx.x * blockDim.x + threadIdx.x;  // float4 index
  const int nkv = NB * SS * FF / 4;
  const float* src; short* dst;
  if (i < nkv){
    int idx = i * 4;
    int row = idx >> 10, col = idx & 1023;
    int b = row >> 11, s = row & 2047;
    src = (s < MMEM) ? (mem + ((size_t)b*MMEM + s)*FF + col)
                     : (x   + ((size_t)b*TT + (s - MMEM))*FF + col);
    dst = kv + (size_t)i * 4;
  } else {
    int j = i - nkv;
    if (j >= SS * FF / 4) return;
    src = rel + (size_t)j * 4;
    dst = relo + (size_t)j * 4;
  }
  float4 v = *(const float4*)src;
  short4 o; o.x = f2bf(v.x); o.y = f2bf(v.y); o.z = f2bf(v.z); o.w = f2bf(v.w);
  *(short4*)dst = o;
}

// batched: out_z[c][r] = in_z[r][c], 1024x1024, f32 -> bf16
__global__ void transpose_cast5(const float* __restrict__ i0, const float* __restrict__ i1,
                                const float* __restrict__ i2, const float* __restrict__ i3,
                                const float* __restrict__ i4,
                                short* __restrict__ o0, short* __restrict__ o1,
                                short* __restrict__ o2, short* __restrict__ o3,
                                short* __restrict__ o4){
  const float* in; short* out;
  switch (blockIdx.z){
    case 0: in = i0; out = o0; break;
    case 1: in = i1; out = o1; break;
    case 2: in = i2; out = o2; break;
    case 3: in = i3; out = o3; break;
    default: in = i4; out = o4; break;
  }
  __shared__ float tile[32][33];
  int bx = blockIdx.x * 32, by = blockIdx.y * 32;
  int tx = threadIdx.x, ty = threadIdx.y;
  for (int j = ty; j < 32; j += 8)
    tile[j][tx] = in[(size_t)(by + j)*1024 + bx + tx];
  __syncthreads();
  for (int j = ty; j < 32; j += 8)
    out[(size_t)(bx + j)*1024 + by + tx] = f2bf(tile[tx][j]);
}

// ki[b, 0:M] = episode_idx; ki[b, M+t] = episode_idx[b,M-1] + cumsum(dones)[t]
// Also per 16-row q-group: valid-key interval [s_lo, s_hi) (ki nondecreasing
// -> episode-match set contiguous; outside tiles fully masked -> skippable).
__global__ void scan_kernel(const int* __restrict__ episode_idx, const int* __restrict__ dones,
                            int* __restrict__ ki, int2* __restrict__ ranges){
  __shared__ int buf[TT];
  __shared__ int kis[SS];
  int b = blockIdx.x, t = threadIdx.x;
  buf[t] = dones[b*TT + t];
  kis[t] = episode_idx[b*MMEM + t];
  __syncthreads();
  for (int off = 1; off < TT; off <<= 1){
    int v = (t >= off) ? buf[t - off] : 0;
    __syncthreads();
    buf[t] += v;
    __syncthreads();
  }
  int base = kis[MMEM - 1];
  int q = base + buf[t];
  kis[MMEM + t] = q;
  ki[b*SS + t] = kis[t];
  ki[b*SS + MMEM + t] = q;
  __syncthreads();
  if (t < 64){
    const int qlo = kis[MMEM + t*16];
    const int qhi = kis[MMEM + t*16 + 15];
    int lo = 0, hi = SS;
    while (lo < hi){ int mid = (lo + hi) >> 1; if (kis[mid] < qlo) lo = mid + 1; else hi = mid; }
    const int s_lo = lo;
    lo = 0; hi = SS;
    const int tgt = qhi + 1;
    while (lo < hi){ int mid = (lo + hi) >> 1; if (kis[mid] < tgt) lo = mid + 1; else hi = mid; }
    int s_hi = lo;                              // exclusive
    const int cap = t*16 + 15 + MMEM + 1;       // causal cap (<= SS always)
    if (s_hi > cap) s_hi = cap;
    ranges[(b << 6) + t] = make_int2(s_lo, s_hi);
  }
}

// uk[b,n,s] = sum_h u[n,h]*k[b,s,n,h];  vr[n,j] = sum_h v[n,h]*r[j,n,h]
__global__ void bias_tables(const short* __restrict__ kbf, const short* __restrict__ rbf,
                            const float* __restrict__ u, const float* __restrict__ v,
                            float* __restrict__ uk, float* __restrict__ vr){
  int i = blockIdx.x * blockDim.x + threadIdx.x;
  const short* p; const float* w; float* outp;
  if (i < NB * NHD * SS){
    int s = i & 2047, n = (i >> 11) & 15, b = i >> 15;
    p = kbf + (size_t)(b * SS + s) * 1024 + n * 64;
    w = u + n * 64;
    outp = uk + (size_t)(b * NHD + n) * SS + s;
  } else {
    int j = i - NB * NHD * SS;
    if (j >= NHD * SS) return;
    int jj = j & 2047, n = j >> 11;
    p = rbf + (size_t)jj * 1024 + n * 64;
    w = v + n * 64;
    outp = vr + (size_t)n * SS + jj;
  }
  float acc = 0.f;
  #pragma unroll
  for (int c = 0; c < 8; c++){
    bf16x8 kv8 = *(const bf16x8*)(p + c * 8);
    float4 w0 = *(const float4*)(w + c * 8);
    float4 w1 = *(const float4*)(w + c * 8 + 4);
    acc += bf2f(kv8[0])*w0.x + bf2f(kv8[1])*w0.y + bf2f(kv8[2])*w0.z + bf2f(kv8[3])*w0.w
         + bf2f(kv8[4])*w1.x + bf2f(kv8[5])*w1.y + bf2f(kv8[6])*w1.z + bf2f(kv8[7])*w1.w;
  }
  *outp = acc;
}

// ------------- 256x64 GEMM core, BK=64, XOR-swizzled staging ----------------
// C[i,j] = sum_k A[i,k]*BT[j,k]; row-major bf16, ld=1024, K=1024.
// M-tile doubled vs R9 (128->256): 32 MFMA/wave/iter vs 16 — R9 showed the
// per-iter barrier drain still dominated (MfmaUtil 18%) even at 6 blocks/CU;
// the lever is MFMA-per-drain, not more co-resident drains. LDS 40 KB ->
// 4 blocks/CU. Unit swizzle: unit u=(j*256+tid) -> row=u>>3 (=j*32+(tid>>3)),
// global chunk=(tid&7)^((tid>>3)&7) (j-independent -> ONE base pointer per
// operand, low VGPR). Readers: chunk q of row at LDS slot q^(row&7).
// R8/R9 verified: SQ_LDS_BANK_CONFLICT == 0 with this layout.
__device__ __forceinline__ void gemm_core_256x64(const short* __restrict__ A,
                                                 const short* __restrict__ BT,
                                                 int row0, int col0,
                                                 short* As, short* Bs,
                                                 f32x4 (&acc)[8][2]){
  const int tid = threadIdx.x;
  const int lane = tid & 63, wv = tid >> 6;
  const int lcol = lane & 15, quad = lane >> 4;
  const int wr = (wv >> 1) * 128, wc = (wv & 1) * 32;
  const int sw = lcol & 7;
  const int ch0 = (quad ^ sw) * 8;
  const int ch1 = ((4 + quad) ^ sw) * 8;

  #pragma unroll
  for (int r = 0; r < 8; r++)
    #pragma unroll
    for (int c = 0; c < 2; c++) acc[r][c] = (f32x4){0.f, 0.f, 0.f, 0.f};

  const int chk = (tid & 7) ^ ((tid >> 3) & 7);
  const short* gA0 = A  + (size_t)(row0 + (tid >> 3)) * 1024 + chk * 8;
  const short* gB0 = BT + (size_t)(col0 + (tid >> 3)) * 1024 + chk * 8;
  short* dA0 = As + wv * 512;   // + j*2048 per stage
  short* dB0 = Bs + wv * 512;

  #pragma unroll 1
  for (int k0 = 0; k0 < 1024; k0 += 64){
    __syncthreads();
    #pragma unroll
    for (int j = 0; j < 8; j++)
      stage16(gA0 + (size_t)j * 32768 + k0, dA0 + j * 2048);
    #pragma unroll
    for (int j = 0; j < 2; j++)
      stage16(gB0 + (size_t)j * 32768 + k0, dB0 + j * 2048);
    __syncthreads();
    bf16x8 bfr[2][2];
    #pragma unroll
    for (int c = 0; c < 2; c++){
      const int rb = (wc + c * 16 + lcol) * 64;
      bfr[c][0] = *(const bf16x8*)&Bs[rb + ch0];
      bfr[c][1] = *(const bf16x8*)&Bs[rb + ch1];
    }
    #pragma unroll
    for (int r = 0; r < 8; r++){
      const int rb = (wr + r * 16 + lcol) * 64;
      bf16x8 a0 = *(const bf16x8*)&As[rb + ch0];
      bf16x8 a1 = *(const bf16x8*)&As[rb + ch1];
      #pragma unroll
      for (int c = 0; c < 2; c++){
        acc[r][c] = __builtin_amdgcn_mfma_f32_16x16x32_bf16(a0, bfr[c][0], acc[r][c], 0, 0, 0);
        acc[r][c] = __builtin_amdgcn_mfma_f32_16x16x32_bf16(a1, bfr[c][1], acc[r][c], 0, 0, 0);
      }
    }
  }
}

// ------------- 128x64 GEMM core (kept for out_gemm) -------------------------
__device__ __forceinline__ void gemm_core_128x64(const short* __restrict__ A,
                                                 const short* __restrict__ BT,
                                                 int row0, int col0,
                                                 short* As, short* Bs,
                                                 f32x4 (&acc)[4][2]){
  const int tid = threadIdx.x;
  const int lane = tid & 63, wv = tid >> 6;
  const int lcol = lane & 15, quad = lane >> 4;
  const int wr = (wv >> 1) * 64, wc = (wv & 1) * 32;
  const int sw = lcol & 7;
  const int ch0 = (quad ^ sw) * 8;
  const int ch1 = ((4 + quad) ^ sw) * 8;

  #pragma unroll
  for (int r = 0; r < 4; r++)
    #pragma unroll
    for (int c = 0; c < 2; c++) acc[r][c] = (f32x4){0.f, 0.f, 0.f, 0.f};

  const int chk = (tid & 7) ^ ((tid >> 3) & 7);
  const short* gA0 = A  + (size_t)(row0 + (tid >> 3)) * 1024 + chk * 8;
  const short* gB0 = BT + (size_t)(col0 + (tid >> 3)) * 1024 + chk * 8;
  short* dA0 = As + wv * 512;
  short* dB0 = Bs + wv * 512;

  #pragma unroll 1
  for (int k0 = 0; k0 < 1024; k0 += 64){
    __syncthreads();
    #pragma unroll
    for (int j = 0; j < 4; j++)
      stage16(gA0 + (size_t)j * 32768 + k0, dA0 + j * 2048);
    stage16(gB0 + k0, dB0);
    stage16(gB0 + 32768 + k0, dB0 + 2048);
    __syncthreads();
    bf16x8 bfr[2][2];
    #pragma unroll
    for (int c = 0; c < 2; c++){
      const int rb = (wc + c * 16 + lcol) * 64;
      bfr[c][0] = *(const bf16x8*)&Bs[rb + ch0];
      bfr[c][1] = *(const bf16x8*)&Bs[rb + ch1];
    }
    #pragma unroll
    for (int r = 0; r < 4; r++){
      const int rb = (wr + r * 16 + lcol) * 64;
      bf16x8 a0 = *(const bf16x8*)&As[rb + ch0];
      bf16x8 a1 = *(const bf16x8*)&As[rb + ch1];
      #pragma unroll
      for (int c = 0; c < 2; c++){
        acc[r][c] = __builtin_amdgcn_mfma_f32_16x16x32_bf16(a0, bfr[c][0], acc[r][c], 0, 0, 0);
        acc[r][c] = __builtin_amdgcn_mfma_f32_16x16x32_bf16(a1, bfr[c][1], acc[r][c], 0, 0, 0);
      }
    }
  }
}

// Fused projection GEMM (256x64 tiles): blockIdx.z selects job:
//   z=0: kbf = kv @ WkT                      (4096 rows, bx<16)
//   z=1: vT  = kv @ WvT, per-head transposed (4096 rows, bx<16)
//   z=2: qb  = x @ WqT   (x in-place from kv rows [M..S); bx<8)
//   z=3: rbf = rel @ WrT (2048 rows; bx<8)
__global__ __launch_bounds__(256) void proj_gemm(
    const short* __restrict__ kv, const short* __restrict__ relb,
    const short* __restrict__ WkT, const short* __restrict__ WvT,
    const short* __restrict__ WqT, const short* __restrict__ WrT,
    short* __restrict__ kbf, short* __restrict__ vT,
    short* __restrict__ qb, short* __restrict__ rbf){
  const int z = blockIdx.z;
  const int bx = blockIdx.x;
  const short* A; const short* BT;
  int row0 = bx * 256, qbb = 0;
  if (z == 0){ A = kv; BT = WkT; }
  else if (z == 1){ A = kv; BT = WvT; }
  else if (z == 2){
    if (bx >= 8) return;
    qbb = bx >> 2;                       // batch
    A = kv + (size_t)(qbb * SS + MMEM) * 1024;   // x rows live inside kv
    row0 = (bx & 3) * 256;
    BT = WqT;
  }
  else { if (bx >= 8) return; A = relb; BT = WrT; }
  const int col0 = blockIdx.y * 64;

  __shared__ __align__(16) short As[256*64];
  __shared__ __align__(16) short Bs[64*64];
  f32x4 acc[8][2];
  gemm_core_256x64(A, BT, row0, col0, As, Bs, acc);

  const int lane = threadIdx.x & 63, wv = threadIdx.x >> 6;
  const int lcol = lane & 15, quad = lane >> 4;
  const int wr = (wv >> 1) * 128, wc = (wv & 1) * 32;
  #pragma unroll
  for (int c = 0; c < 2; c++){
    const int cc = col0 + wc + c*16 + lcol;
    #pragma unroll
    for (int r = 0; r < 8; r++){
      #pragma unroll
      for (int ri = 0; ri < 4; ri++){
        const int rr = row0 + wr + r*16 + quad*4 + ri;
        float val = acc[r][c][ri];
        if (z == 0){
          kbf[(size_t)rr * 1024 + cc] = f2bf(val);
        } else if (z == 1){
          int b = rr >> 11, s = rr & 2047;
          vT[(size_t)(((b << 4) + (cc >> 6)) * 64 + (cc & 63)) * 2048 + s] = f2bf(val);
        } else if (z == 2){
          qb[((size_t)(qbb * TT) + rr) * 1024 + cc] = f2bf(val);
        } else {
          rbf[(size_t)rr * 1024 + cc] = f2bf(val);
        }
      }
    }
  }
}

// Output projection: out = attn @ WoT + b_out (f32 out, 2048 rows)
__global__ __launch_bounds__(256) void out_gemm(const short* __restrict__ A,
                                                const short* __restrict__ BT,
                                                const float* __restrict__ bias,
                                                float* __restrict__ C){
  const int row0 = blockIdx.x * 128, col0 = blockIdx.y * 64;
  __shared__ __align__(16) short As[128*64];
  __shared__ __align__(16) short Bs[64*64];
  f32x4 acc[4][2];
  gemm_core_128x64(A, BT, row0, col0, As, Bs, acc);

  const int lane = threadIdx.x & 63, wv = threadIdx.x >> 6;
  const int lcol = lane & 15, quad = lane >> 4;
  const int wr = (wv >> 1) * 64, wc = (wv & 1) * 32;
  #pragma unroll
  for (int c = 0; c < 2; c++){
    const int cc = col0 + wc + c*16 + lcol;
    const float bb = bias[cc];
    #pragma unroll
    for (int r = 0; r < 4; r++)
      #pragma unroll
      for (int ri = 0; ri < 4; ri++){
        const int rr = row0 + wr + r*16 + quad*4 + ri;
        C[(size_t)rr * 1024 + cc] = acc[r][c][ri] + bb;
      }
  }
}

// ---------------- flash attention: one wave per 16-row q-group --------------
// grid 2048 x 64 threads. XCD swizzle (L2 working set per XCD ~3.6 MB).
// Each wave sweeps ONLY the valid k-tile interval from ranges[].
__global__ __launch_bounds__(64) void attn_kernel(const short* __restrict__ qb,
                            const short* __restrict__ rbf,
                            const short* __restrict__ kk, const short* __restrict__ vT,
                            const int* __restrict__ ki,
                            const float* __restrict__ uk, const float* __restrict__ vr,
                            const int2* __restrict__ ranges,
                            short* __restrict__ attn_out){
  const int blk = blockIdx.x;
  const int xcd = blk & 7;
  const int idx = blk >> 3;                 // [0,256)
  const int bn  = (xcd << 2) | (idx >> 6);  // 4 (b,n) groups per XCD
  const int t16 = (idx & 63) * 16;
  const int n = bn & 15;
  const int b = bn >> 4;
  const int lane = threadIdx.x & 63;
  const int quad = lane >> 4, lcol = lane & 15;

  __shared__ __align__(16) short pb[16 * 72];

  const short* qp = qb + (size_t)(b * TT + t16 + lcol) * 1024 + n * 64 + quad * 8;
  bf16x8 aq0 = *(const bf16x8*)(qp);
  bf16x8 aq1 = *(const bf16x8*)(qp + 32);

  int trow[4], qi_r[4], sl[4];
  bool hi[4];
  #pragma unroll
  for (int r = 0; r < 4; r++){
    trow[r] = t16 + quad * 4 + r;
    qi_r[r] = ki[b * SS + MMEM + trow[r]];
    const int rt = quad * 4 + r;
    const int off = lcol + 15 - rt;
    sl[r] = quad * 16 + (off & 15);
    hi[r] = off >= 16;
  }

  float m_run[4], l_run[4];
  f32x4 o[4];
  #pragma unroll
  for (int r = 0; r < 4; r++){ m_run[r] = -1e30f; l_run[r] = 0.f; }
  #pragma unroll
  for (int c = 0; c < 4; c++) o[c] = (f32x4){0.f, 0.f, 0.f, 0.f};

  const float scale = 0.125f;
  const size_t vt_base = (size_t)((b * NHD + n) * HD);
  const short* rb_head = rbf + n * 64;
  const float* uk_row = uk + (size_t)(b * NHD + n) * SS;
  const float* vr_row = vr + (size_t)n * SS;

  const int2 rg = ranges[(b << 6) + (t16 >> 4)];
  const int kt0 = rg.x >> 6, kt1 = (rg.y - 1) >> 6;

  for (int kt = kt0; kt <= kt1; kt++){
    const int s0 = kt * 64;
    // ---- S = Q . K^T  (+ uk column bias) ----
    f32x4 sacc[4];
    float ukc[4];
    #pragma unroll
    for (int c = 0; c < 4; c++){
      const short* kp = kk + (size_t)(b * SS + s0 + 16 * c + lcol) * 1024 + n * 64 + quad * 8;
      bf16x8 b0 = *(const bf16x8*)(kp);
      bf16x8 b1 = *(const bf16x8*)(kp + 32);
      f32x4 z = (f32x4){0.f, 0.f, 0.f, 0.f};
      z = __builtin_amdgcn_mfma_f32_16x16x32_bf16(aq0, b0, z, 0, 0, 0);
      z = __builtin_amdgcn_mfma_f32_16x16x32_bf16(aq1, b1, z, 0, 0, 0);
      sacc[c] = z;
      ukc[c] = uk_row[s0 + 16 * c + lcol];
    }
    int ki_c[4];
    #pragma unroll
    for (int c = 0; c < 4; c++) ki_c[c] = ki[b * SS + s0 + 16 * c + lcol];

    // ---- D = Q . R^T (+ vr column bias) over the 80-row window ----
    const int j0 = s0 - t16 + 1008;   // >= 0 always
    f32x4 Dw[5];
    #pragma unroll
    for (int c5 = 0; c5 < 5; c5++){
      int jr = j0 + 16 * c5 + lcol;
      jr = (jr > SS - 1) ? (SS - 1) : jr;   // clamped rows are causally masked
      const short* rp = rb_head + (size_t)jr * 1024 + quad * 8;
      bf16x8 r0 = *(const bf16x8*)(rp);
      bf16x8 r1 = *(const bf16x8*)(rp + 32);
      f32x4 z = (f32x4){0.f, 0.f, 0.f, 0.f};
      z = __builtin_amdgcn_mfma_f32_16x16x32_bf16(aq0, r0, z, 0, 0, 0);
      z = __builtin_amdgcn_mfma_f32_16x16x32_bf16(aq1, r1, z, 0, 0, 0);
      const float vrj = vr_row[jr];
      #pragma unroll
      for (int r = 0; r < 4; r++) z[r] += vrj;
      Dw[c5] = z;
    }

    // ---- bias shift (Toeplitz) + mask + logits ----
    float p[4][4];
    float rowmax[4];
    #pragma unroll
    for (int r = 0; r < 4; r++) rowmax[r] = -1e30f;
    #pragma unroll
    for (int c = 0; c < 4; c++){
      const int s = s0 + 16 * c + lcol;
      #pragma unroll
      for (int r = 0; r < 4; r++){
        const float v0 = __shfl(Dw[c][r], sl[r], 64);
        const float v1 = __shfl(Dw[c + 1][r], sl[r], 64);
        const float bd = hi[r] ? v1 : v0;
        float lg = (sacc[c][r] + ukc[c] + bd) * scale;
        const bool valid = (s <= trow[r] + MMEM) && (ki_c[c] == qi_r[r]);
        lg = valid ? lg : -1e30f;
        p[c][r] = lg;
        rowmax[r] = fmaxf(rowmax[r], lg);
      }
    }
    // ---- online softmax ----
    #pragma unroll
    for (int r = 0; r < 4; r++){
      float vmx = rowmax[r];
      #pragma unroll
      for (int off = 1; off < 16; off <<= 1) vmx = fmaxf(vmx, __shfl_xor(vmx, off, 64));
      float mnew = fmaxf(m_run[r], vmx);
      float alpha = __expf(m_run[r] - mnew);
      m_run[r] = mnew;
      l_run[r] *= alpha;
      #pragma unroll
      for (int c = 0; c < 4; c++) o[c][r] *= alpha;
    }
    float psum[4] = {0.f, 0.f, 0.f, 0.f};
    #pragma unroll
    for (int c = 0; c < 4; c++)
      #pragma unroll
      for (int r = 0; r < 4; r++){
        float pv = __expf(p[c][r] - m_run[r]);
        p[c][r] = pv;
        psum[r] += pv;
      }
    #pragma unroll
    for (int r = 0; r < 4; r++){
      float vs = psum[r];
      #pragma unroll
      for (int off = 1; off < 16; off <<= 1) vs += __shfl_xor(vs, off, 64);
      l_run[r] += vs;
    }
    // ---- P: C-layout -> A-layout via LDS (wave-synchronous) ----
    #pragma unroll
    for (int c = 0; c < 4; c++)
      #pragma unroll
      for (int r = 0; r < 4; r++)
        pb[(quad * 4 + r) * 72 + 16 * c + lcol] = f2bf(p[c][r]);
    bf16x8 pa0 = *(const bf16x8*)(&pb[lcol * 72 + quad * 8]);
    bf16x8 pa1 = *(const bf16x8*)(&pb[lcol * 72 + 32 + quad * 8]);
    // ---- O += P . V ----
    #pragma unroll
    for (int c = 0; c < 4; c++){
      const short* vtp = vT + (vt_base + c * 16 + lcol) * (size_t)SS + s0 + quad * 8;
      bf16x8 bv0 = *(const bf16x8*)(vtp);
      bf16x8 bv1 = *(const bf16x8*)(vtp + 32);
      o[c] = __builtin_amdgcn_mfma_f32_16x16x32_bf16(pa0, bv0, o[c], 0, 0, 0);
      o[c] = __builtin_amdgcn_mfma_f32_16x16x32_bf16(pa1, bv1, o[c], 0, 0, 0);
    }
  }

  // ---- epilogue: normalize, store bf16 attn [B*T, N*H] ----
  #pragma unroll
  for (int r = 0; r < 4; r++){
    const float inv = 1.f / l_run[r];
    const int t = trow[r];
    #pragma unroll
    for (int c = 0; c < 4; c++)
      attn_out[(size_t)(b * TT + t) * 1024 + n * 64 + c * 16 + lcol] = f2bf(o[c][r] * inv);
  }
}

// ---------------- launcher ----------------
extern "C" void kernel_launch(void* const* d_in, const int* in_sizes, int n_in,
                              void* d_out, int out_size, void* d_ws, size_t ws_size,
                              hipStream_t stream){
  const float* x      = (const float*)d_in[0];
  const float* rel    = (const float*)d_in[1];
  const float* memory = (const float*)d_in[2];
  const int*   episode_idx = (const int*)d_in[3];
  const int*   dones  = (const int*)d_in[4];
  const float* Wq  = (const float*)d_in[5];
  const float* Wk  = (const float*)d_in[6];
  const float* Wv  = (const float*)d_in[7];
  const float* Wr  = (const float*)d_in[8];
  const float* u   = (const float*)d_in[9];
  const float* v   = (const float*)d_in[10];
  const float* Wout  = (const float*)d_in[11];
  const float* b_out = (const float*)d_in[12];
  float* out = (float*)d_out;

  char* ws = (char*)d_ws;
  size_t off = 0;
  auto alloc = [&](size_t bytes) -> char* {
    char* p = ws + off;
    off += (bytes + 255) & ~(size_t)255;
    return p;
  };
  short* kv_bf  = (short*)alloc((size_t)NB * SS * FF * 2);
  short* rel_bf = (short*)alloc((size_t)SS * FF * 2);
  short* WqT    = (short*)alloc((size_t)FF * 1024 * 2);
  short* WkT    = (short*)alloc((size_t)FF * 1024 * 2);
  short* WvT    = (short*)alloc((size_t)FF * 1024 * 2);
  short* WrT    = (short*)alloc((size_t)FF * 1024 * 2);
  short* WoT    = (short*)alloc((size_t)FF * 1024 * 2);
  short* qbuf   = (short*)alloc((size_t)NB * TT * 1024 * 2);
  short* kbf    = (short*)alloc((size_t)NB * SS * 1024 * 2);
  short* vTb    = (short*)alloc((size_t)NB * SS * 1024 * 2);
  short* rbf    = (short*)alloc((size_t)SS * 1024 * 2);
  int*   ki     = (int*)  alloc((size_t)NB * SS * 4);
  int2*  ranges = (int2*) alloc((size_t)NB * 64 * 8);
  float* ukT    = (float*)alloc((size_t)NB * NHD * SS * 4);
  float* vrT    = (float*)alloc((size_t)NHD * SS * 4);
  short* attn   = (short*)alloc((size_t)NB * TT * 1024 * 2);
  (void)ws_size; (void)in_sizes; (void)n_in; (void)out_size;

  // pack (fused kv + rel cast)
  const int n4 = NB*SS*FF/4 + SS*FF/4;
  build_inputs<<<(n4 + 255)/256, 256, 0, stream>>>(memory, x, rel, kv_bf, rel_bf);
  dim3 tb(32, 8), tg5(32, 32, 5);
  transpose_cast5<<<tg5, tb, 0, stream>>>(Wq, Wk, Wv, Wr, Wout, WqT, WkT, WvT, WrT, WoT);
  scan_kernel<<<NB, TT, 0, stream>>>(episode_idx, dones, ki, ranges);

  // fused projections, 256x64 tiles: z=0 K, z=1 V(T), z=2 Q, z=3 R
  proj_gemm<<<dim3(16, 16, 4), 256, 0, stream>>>(kv_bf, rel_bf,
                                                 WkT, WvT, WqT, WrT,
                                                 kbf, vTb, qbuf, rbf);

  // u·k / v·r column-bias tables
  bias_tables<<<(NB*NHD*SS + NHD*SS + 255)/256, 256, 0, stream>>>(kbf, rbf, u, v, ukT, vrT);

  // attention: one wave per 16-row q-group, valid-interval sweep only
  attn_kernel<<<2048, 64, 0, stream>>>(qbuf, rbf, kbf, vTb, ki, ukT, vrT, ranges, attn);

  // output projection
  out_gemm<<<dim3(16, 16), 256, 0, stream>>>(attn, WoT, b_out, out);
}

// Round 11
// 225.692 us; speedup vs baseline: 1.0559x; 1.0559x over previous
//
#include <hip/hip_runtime.h>
#include <cstdint>
#include <cstddef>

// Problem constants
#define NB 2
#define TT 1024
#define MMEM 1024
#define SS 2048   // M + T
#define FF 1024
#define NHD 16    // heads
#define HD 64     // head dim

typedef __attribute__((ext_vector_type(8))) short bf16x8;
typedef __attribute__((ext_vector_type(4))) float f32x4;

__device__ __forceinline__ float bf2f(short s){
  unsigned u = ((unsigned)(unsigned short)s) << 16;
  float f; __builtin_memcpy(&f, &u, 4); return f;
}
__device__ __forceinline__ short f2bf(float f){
  unsigned u; __builtin_memcpy(&u, &f, 4);
  u += 0x7fffu + ((u >> 16) & 1u);   // RNE
  return (short)(u >> 16);
}

// async global->LDS, 16 B per lane; LDS dest = wave-uniform base + lane*16
typedef const __attribute__((address_space(1))) void gv_t;
typedef __attribute__((address_space(3))) void lv_t;
__device__ __forceinline__ void stage16(const void* g, void* l){
  __builtin_amdgcn_global_load_lds((gv_t*)g, (lv_t*)l, 16, 0, 0);
}

// ---------------- pack / cast kernels ----------------

// fused: kv_bf = bf16(concat(memory, x)) [B*SS,FF]; rel_bf = bf16(rel) [SS,FF]
__global__ void build_inputs(const float* __restrict__ mem, const float* __restrict__ x,
                             const float* __restrict__ rel,
                             short* __restrict__ kv, short* __restrict__ relo){
  int i = blockIdx.x * blockDim.x + threadIdx.x;  // float4 index
  const int nkv = NB * SS * FF / 4;
  const float* src; short* dst;
  if (i < nkv){
    int idx = i * 4;
    int row = idx >> 10, col = idx & 1023;
    int b = row >> 11, s = row & 2047;
    src = (s < MMEM) ? (mem + ((size_t)b*MMEM + s)*FF + col)
                     : (x   + ((size_t)b*TT + (s - MMEM))*FF + col);
    dst = kv + (size_t)i * 4;
  } else {
    int j = i - nkv;
    if (j >= SS * FF / 4) return;
    src = rel + (size_t)j * 4;
    dst = relo + (size_t)j * 4;
  }
  float4 v = *(const float4*)src;
  short4 o; o.x = f2bf(v.x); o.y = f2bf(v.y); o.z = f2bf(v.z); o.w = f2bf(v.w);
  *(short4*)dst = o;
}

// batched: out_z[c][r] = in_z[r][c], 1024x1024, f32 -> bf16
__global__ void transpose_cast5(const float* __restrict__ i0, const float* __restrict__ i1,
                                const float* __restrict__ i2, const float* __restrict__ i3,
                                const float* __restrict__ i4,
                                short* __restrict__ o0, short* __restrict__ o1,
                                short* __restrict__ o2, short* __restrict__ o3,
                                short* __restrict__ o4){
  const float* in; short* out;
  switch (blockIdx.z){
    case 0: in = i0; out = o0; break;
    case 1: in = i1; out = o1; break;
    case 2: in = i2; out = o2; break;
    case 3: in = i3; out = o3; break;
    default: in = i4; out = o4; break;
  }
  __shared__ float tile[32][33];
  int bx = blockIdx.x * 32, by = blockIdx.y * 32;
  int tx = threadIdx.x, ty = threadIdx.y;
  for (int j = ty; j < 32; j += 8)
    tile[j][tx] = in[(size_t)(by + j)*1024 + bx + tx];
  __syncthreads();
  for (int j = ty; j < 32; j += 8)
    out[(size_t)(bx + j)*1024 + by + tx] = f2bf(tile[tx][j]);
}

// ki[b, 0:M] = episode_idx; ki[b, M+t] = episode_idx[b,M-1] + cumsum(dones)[t]
// Also per 16-row q-group: valid-key interval [s_lo, s_hi) (ki nondecreasing
// -> episode-match set contiguous; outside tiles fully masked -> skippable).
// Wave shfl-scan (2 barriers vs Hillis-Steele's 20).
__global__ void scan_kernel(const int* __restrict__ episode_idx, const int* __restrict__ dones,
                            int* __restrict__ ki, int2* __restrict__ ranges){
  __shared__ int kis[SS];
  __shared__ int wsum[16];
  const int b = blockIdx.x, t = threadIdx.x;
  const int lane = t & 63, wv = t >> 6;
  int v = dones[b*TT + t];
  kis[t] = episode_idx[b*MMEM + t];
  #pragma unroll
  for (int off = 1; off < 64; off <<= 1){
    int tmp = __shfl_up(v, off, 64);
    if (lane >= off) v += tmp;
  }
  if (lane == 63) wsum[wv] = v;
  __syncthreads();
  int add = 0;
  for (int w = 0; w < wv; w++) add += wsum[w];
  v += add;                              // inclusive cumsum(dones)[t]
  const int base = kis[MMEM - 1];
  const int q = base + v;
  kis[MMEM + t] = q;
  ki[b*SS + t] = kis[t];
  ki[b*SS + MMEM + t] = q;
  __syncthreads();
  if (t < 64){
    const int qlo = kis[MMEM + t*16];
    const int qhi = kis[MMEM + t*16 + 15];
    int lo = 0, hi = SS;
    while (lo < hi){ int mid = (lo + hi) >> 1; if (kis[mid] < qlo) lo = mid + 1; else hi = mid; }
    const int s_lo = lo;
    lo = 0; hi = SS;
    const int tgt = qhi + 1;
    while (lo < hi){ int mid = (lo + hi) >> 1; if (kis[mid] < tgt) lo = mid + 1; else hi = mid; }
    int s_hi = lo;                              // exclusive
    const int cap = t*16 + 15 + MMEM + 1;       // causal cap (<= SS always)
    if (s_hi > cap) s_hi = cap;
    ranges[(b << 6) + t] = make_int2(s_lo, s_hi);
  }
}

// uk[b,n,s] = sum_h u[n,h]*k[b,s,n,h];  vr[n,j] = sum_h v[n,h]*r[j,n,h]
__global__ void bias_tables(const short* __restrict__ kbf, const short* __restrict__ rbf,
                            const float* __restrict__ u, const float* __restrict__ v,
                            float* __restrict__ uk, float* __restrict__ vr){
  int i = blockIdx.x * blockDim.x + threadIdx.x;
  const short* p; const float* w; float* outp;
  if (i < NB * NHD * SS){
    int s = i & 2047, n = (i >> 11) & 15, b = i >> 15;
    p = kbf + (size_t)(b * SS + s) * 1024 + n * 64;
    w = u + n * 64;
    outp = uk + (size_t)(b * NHD + n) * SS + s;
  } else {
    int j = i - NB * NHD * SS;
    if (j >= NHD * SS) return;
    int jj = j & 2047, n = j >> 11;
    p = rbf + (size_t)jj * 1024 + n * 64;
    w = v + n * 64;
    outp = vr + (size_t)n * SS + jj;
  }
  float acc = 0.f;
  #pragma unroll
  for (int c = 0; c < 8; c++){
    bf16x8 kv8 = *(const bf16x8*)(p + c * 8);
    float4 w0 = *(const float4*)(w + c * 8);
    float4 w1 = *(const float4*)(w + c * 8 + 4);
    acc += bf2f(kv8[0])*w0.x + bf2f(kv8[1])*w0.y + bf2f(kv8[2])*w0.z + bf2f(kv8[3])*w0.w
         + bf2f(kv8[4])*w1.x + bf2f(kv8[5])*w1.y + bf2f(kv8[6])*w1.z + bf2f(kv8[7])*w1.w;
  }
  *outp = acc;
}

// ------------- 128x64 GEMM core, BK=64, XOR-swizzled staging ----------------
// R9's verified best (52.7 us, 0 bank conflicts). R8 (128x128)=56.4,
// R10 (256x64)=63 — tile space mapped, this is the sweet spot for K=1024.
__device__ __forceinline__ void gemm_core_128x64(const short* __restrict__ A,
                                                 const short* __restrict__ BT,
                                                 int row0, int col0,
                                                 short* As, short* Bs,
                                                 f32x4 (&acc)[4][2]){
  const int tid = threadIdx.x;
  const int lane = tid & 63, wv = tid >> 6;
  const int lcol = lane & 15, quad = lane >> 4;
  const int wr = (wv >> 1) * 64, wc = (wv & 1) * 32;
  const int sw = lcol & 7;
  const int ch0 = (quad ^ sw) * 8;
  const int ch1 = ((4 + quad) ^ sw) * 8;

  #pragma unroll
  for (int r = 0; r < 4; r++)
    #pragma unroll
    for (int c = 0; c < 2; c++) acc[r][c] = (f32x4){0.f, 0.f, 0.f, 0.f};

  const int chk = (tid & 7) ^ ((tid >> 3) & 7);
  const short* gA0 = A  + (size_t)(row0 + (tid >> 3)) * 1024 + chk * 8;
  const short* gB0 = BT + (size_t)(col0 + (tid >> 3)) * 1024 + chk * 8;
  short* dA0 = As + wv * 512;
  short* dB0 = Bs + wv * 512;

  #pragma unroll 1
  for (int k0 = 0; k0 < 1024; k0 += 64){
    __syncthreads();
    #pragma unroll
    for (int j = 0; j < 4; j++)
      stage16(gA0 + (size_t)j * 32768 + k0, dA0 + j * 2048);
    stage16(gB0 + k0, dB0);
    stage16(gB0 + 32768 + k0, dB0 + 2048);
    __syncthreads();
    bf16x8 bfr[2][2];
    #pragma unroll
    for (int c = 0; c < 2; c++){
      const int rb = (wc + c * 16 + lcol) * 64;
      bfr[c][0] = *(const bf16x8*)&Bs[rb + ch0];
      bfr[c][1] = *(const bf16x8*)&Bs[rb + ch1];
    }
    #pragma unroll
    for (int r = 0; r < 4; r++){
      const int rb = (wr + r * 16 + lcol) * 64;
      bf16x8 a0 = *(const bf16x8*)&As[rb + ch0];
      bf16x8 a1 = *(const bf16x8*)&As[rb + ch1];
      #pragma unroll
      for (int c = 0; c < 2; c++){
        acc[r][c] = __builtin_amdgcn_mfma_f32_16x16x32_bf16(a0, bfr[c][0], acc[r][c], 0, 0, 0);
        acc[r][c] = __builtin_amdgcn_mfma_f32_16x16x32_bf16(a1, bfr[c][1], acc[r][c], 0, 0, 0);
      }
    }
  }
}

// Fused projection GEMM (128x64 tiles): blockIdx.z selects job:
//   z=0: kbf = kv @ WkT                      (4096 rows, bx<32)
//   z=1: vT  = kv @ WvT, per-head transposed (4096 rows, bx<32)
//   z=2: qb  = x @ WqT   (x in-place from kv rows [M..S); bx<16)
//   z=3: rbf = rel @ WrT (2048 rows; bx<16)
// K/V row-tiles entirely below the batch's minimum attended key index
// (ranges[b][group0].x) are SKIPPED: attn never reads K/V there (reads start
// at (s_lo(g) & ~63) >= 128*floor(s_min/128)); any poison leaking into
// masked columns is finite (0xAA bf16 is finite) and multiplied by exactly-0
// probabilities. Exact for any input; ~25% of proj blocks for this data.
__global__ __launch_bounds__(256) void proj_gemm(
    const short* __restrict__ kv, const short* __restrict__ relb,
    const short* __restrict__ WkT, const short* __restrict__ WvT,
    const short* __restrict__ WqT, const short* __restrict__ WrT,
    short* __restrict__ kbf, short* __restrict__ vT,
    short* __restrict__ qb, short* __restrict__ rbf,
    const int2* __restrict__ ranges){
  const int z = blockIdx.z;
  const int bx = blockIdx.x;
  const short* A; const short* BT;
  int row0 = bx * 128, qbb = 0;
  if (z == 0 || z == 1){
    const int bb = row0 >> 11;         // batch
    const int srow = row0 & 2047;      // s-index of tile start
    if (srow + 128 <= ranges[bb << 6].x) return;   // dead K/V rows
    A = kv; BT = (z == 0) ? WkT : WvT;
  }
  else if (z == 2){
    if (bx >= 16) return;
    qbb = bx >> 3;                       // batch
    A = kv + (size_t)(qbb * SS + MMEM) * 1024;   // x rows live inside kv
    row0 = (bx & 7) * 128;
    BT = WqT;
  }
  else { if (bx >= 16) return; A = relb; BT = WrT; }
  const int col0 = blockIdx.y * 64;

  __shared__ __align__(16) short As[128*64];
  __shared__ __align__(16) short Bs[64*64];
  f32x4 acc[4][2];
  gemm_core_128x64(A, BT, row0, col0, As, Bs, acc);

  const int lane = threadIdx.x & 63, wv = threadIdx.x >> 6;
  const int lcol = lane & 15, quad = lane >> 4;
  const int wr = (wv >> 1) * 64, wc = (wv & 1) * 32;
  #pragma unroll
  for (int c = 0; c < 2; c++){
    const int cc = col0 + wc + c*16 + lcol;
    #pragma unroll
    for (int r = 0; r < 4; r++){
      #pragma unroll
      for (int ri = 0; ri < 4; ri++){
        const int rr = row0 + wr + r*16 + quad*4 + ri;
        float val = acc[r][c][ri];
        if (z == 0){
          kbf[(size_t)rr * 1024 + cc] = f2bf(val);
        } else if (z == 1){
          int b = rr >> 11, s = rr & 2047;
          vT[(size_t)(((b << 4) + (cc >> 6)) * 64 + (cc & 63)) * 2048 + s] = f2bf(val);
        } else if (z == 2){
          qb[((size_t)(qbb * TT) + rr) * 1024 + cc] = f2bf(val);
        } else {
          rbf[(size_t)rr * 1024 + cc] = f2bf(val);
        }
      }
    }
  }
}

// Output projection: out = attn @ WoT + b_out (f32 out, 2048 rows)
__global__ __launch_bounds__(256) void out_gemm(const short* __restrict__ A,
                                                const short* __restrict__ BT,
                                                const float* __restrict__ bias,
                                                float* __restrict__ C){
  const int row0 = blockIdx.x * 128, col0 = blockIdx.y * 64;
  __shared__ __align__(16) short As[128*64];
  __shared__ __align__(16) short Bs[64*64];
  f32x4 acc[4][2];
  gemm_core_128x64(A, BT, row0, col0, As, Bs, acc);

  const int lane = threadIdx.x & 63, wv = threadIdx.x >> 6;
  const int lcol = lane & 15, quad = lane >> 4;
  const int wr = (wv >> 1) * 64, wc = (wv & 1) * 32;
  #pragma unroll
  for (int c = 0; c < 2; c++){
    const int cc = col0 + wc + c*16 + lcol;
    const float bb = bias[cc];
    #pragma unroll
    for (int r = 0; r < 4; r++)
      #pragma unroll
      for (int ri = 0; ri < 4; ri++){
        const int rr = row0 + wr + r*16 + quad*4 + ri;
        C[(size_t)rr * 1024 + cc] = acc[r][c][ri] + bb;
      }
  }
}

// ---------------- flash attention: one wave per 16-row q-group --------------
// grid 2048 x 64 threads. XCD swizzle (L2 working set per XCD ~3.6 MB).
// Each wave sweeps ONLY the valid k-tile interval from ranges[].
__global__ __launch_bounds__(64) void attn_kernel(const short* __restrict__ qb,
                            const short* __restrict__ rbf,
                            const short* __restrict__ kk, const short* __restrict__ vT,
                            const int* __restrict__ ki,
                            const float* __restrict__ uk, const float* __restrict__ vr,
                            const int2* __restrict__ ranges,
                            short* __restrict__ attn_out){
  const int blk = blockIdx.x;
  const int xcd = blk & 7;
  const int idx = blk >> 3;                 // [0,256)
  const int bn  = (xcd << 2) | (idx >> 6);  // 4 (b,n) groups per XCD
  const int t16 = (idx & 63) * 16;
  const int n = bn & 15;
  const int b = bn >> 4;
  const int lane = threadIdx.x & 63;
  const int quad = lane >> 4, lcol = lane & 15;

  __shared__ __align__(16) short pb[16 * 72];

  const short* qp = qb + (size_t)(b * TT + t16 + lcol) * 1024 + n * 64 + quad * 8;
  bf16x8 aq0 = *(const bf16x8*)(qp);
  bf16x8 aq1 = *(const bf16x8*)(qp + 32);

  int trow[4], qi_r[4], sl[4];
  bool hi[4];
  #pragma unroll
  for (int r = 0; r < 4; r++){
    trow[r] = t16 + quad * 4 + r;
    qi_r[r] = ki[b * SS + MMEM + trow[r]];
    const int rt = quad * 4 + r;
    const int off = lcol + 15 - rt;
    sl[r] = quad * 16 + (off & 15);
    hi[r] = off >= 16;
  }

  float m_run[4], l_run[4];
  f32x4 o[4];
  #pragma unroll
  for (int r = 0; r < 4; r++){ m_run[r] = -1e30f; l_run[r] = 0.f; }
  #pragma unroll
  for (int c = 0; c < 4; c++) o[c] = (f32x4){0.f, 0.f, 0.f, 0.f};

  const float scale = 0.125f;
  const size_t vt_base = (size_t)((b * NHD + n) * HD);
  const short* rb_head = rbf + n * 64;
  const float* uk_row = uk + (size_t)(b * NHD + n) * SS;
  const float* vr_row = vr + (size_t)n * SS;

  const int2 rg = ranges[(b << 6) + (t16 >> 4)];
  const int kt0 = rg.x >> 6, kt1 = (rg.y - 1) >> 6;

  for (int kt = kt0; kt <= kt1; kt++){
    const int s0 = kt * 64;
    // ---- S = Q . K^T  (+ uk column bias) ----
    f32x4 sacc[4];
    float ukc[4];
    #pragma unroll
    for (int c = 0; c < 4; c++){
      const short* kp = kk + (size_t)(b * SS + s0 + 16 * c + lcol) * 1024 + n * 64 + quad * 8;
      bf16x8 b0 = *(const bf16x8*)(kp);
      bf16x8 b1 = *(const bf16x8*)(kp + 32);
      f32x4 z = (f32x4){0.f, 0.f, 0.f, 0.f};
      z = __builtin_amdgcn_mfma_f32_16x16x32_bf16(aq0, b0, z, 0, 0, 0);
      z = __builtin_amdgcn_mfma_f32_16x16x32_bf16(aq1, b1, z, 0, 0, 0);
      sacc[c] = z;
      ukc[c] = uk_row[s0 + 16 * c + lcol];
    }
    int ki_c[4];
    #pragma unroll
    for (int c = 0; c < 4; c++) ki_c[c] = ki[b * SS + s0 + 16 * c + lcol];

    // ---- D = Q . R^T (+ vr column bias) over the 80-row window ----
    const int j0 = s0 - t16 + 1008;   // >= 0 always
    f32x4 Dw[5];
    #pragma unroll
    for (int c5 = 0; c5 < 5; c5++){
      int jr = j0 + 16 * c5 + lcol;
      jr = (jr > SS - 1) ? (SS - 1) : jr;   // clamped rows are causally masked
      const short* rp = rb_head + (size_t)jr * 1024 + quad * 8;
      bf16x8 r0 = *(const bf16x8*)(rp);
      bf16x8 r1 = *(const bf16x8*)(rp + 32);
      f32x4 z = (f32x4){0.f, 0.f, 0.f, 0.f};
      z = __builtin_amdgcn_mfma_f32_16x16x32_bf16(aq0, r0, z, 0, 0, 0);
      z = __builtin_amdgcn_mfma_f32_16x16x32_bf16(aq1, r1, z, 0, 0, 0);
      const float vrj = vr_row[jr];
      #pragma unroll
      for (int r = 0; r < 4; r++) z[r] += vrj;
      Dw[c5] = z;
    }

    // ---- bias shift (Toeplitz) + mask + logits ----
    float p[4][4];
    float rowmax[4];
    #pragma unroll
    for (int r = 0; r < 4; r++) rowmax[r] = -1e30f;
    #pragma unroll
    for (int c = 0; c < 4; c++){
      const int s = s0 + 16 * c + lcol;
      #pragma unroll
      for (int r = 0; r < 4; r++){
        const float v0 = __shfl(Dw[c][r], sl[r], 64);
        const float v1 = __shfl(Dw[c + 1][r], sl[r], 64);
        const float bd = hi[r] ? v1 : v0;
        float lg = (sacc[c][r] + ukc[c] + bd) * scale;
        const bool valid = (s <= trow[r] + MMEM) && (ki_c[c] == qi_r[r]);
        lg = valid ? lg : -1e30f;
        p[c][r] = lg;
        rowmax[r] = fmaxf(rowmax[r], lg);
      }
    }
    // ---- online softmax ----
    #pragma unroll
    for (int r = 0; r < 4; r++){
      float vmx = rowmax[r];
      #pragma unroll
      for (int off = 1; off < 16; off <<= 1) vmx = fmaxf(vmx, __shfl_xor(vmx, off, 64));
      float mnew = fmaxf(m_run[r], vmx);
      float alpha = __expf(m_run[r] - mnew);
      m_run[r] = mnew;
      l_run[r] *= alpha;
      #pragma unroll
      for (int c = 0; c < 4; c++) o[c][r] *= alpha;
    }
    float psum[4] = {0.f, 0.f, 0.f, 0.f};
    #pragma unroll
    for (int c = 0; c < 4; c++)
      #pragma unroll
      for (int r = 0; r < 4; r++){
        float pv = __expf(p[c][r] - m_run[r]);
        p[c][r] = pv;
        psum[r] += pv;
      }
    #pragma unroll
    for (int r = 0; r < 4; r++){
      float vs = psum[r];
      #pragma unroll
      for (int off = 1; off < 16; off <<= 1) vs += __shfl_xor(vs, off, 64);
      l_run[r] += vs;
    }
    // ---- P: C-layout -> A-layout via LDS (wave-synchronous) ----
    #pragma unroll
    for (int c = 0; c < 4; c++)
      #pragma unroll
      for (int r = 0; r < 4; r++)
        pb[(quad * 4 + r) * 72 + 16 * c + lcol] = f2bf(p[c][r]);
    bf16x8 pa0 = *(const bf16x8*)(&pb[lcol * 72 + quad * 8]);
    bf16x8 pa1 = *(const bf16x8*)(&pb[lcol * 72 + 32 + quad * 8]);
    // ---- O += P . V ----
    #pragma unroll
    for (int c = 0; c < 4; c++){
      const short* vtp = vT + (vt_base + c * 16 + lcol) * (size_t)SS + s0 + quad * 8;
      bf16x8 bv0 = *(const bf16x8*)(vtp);
      bf16x8 bv1 = *(const bf16x8*)(vtp + 32);
      o[c] = __builtin_amdgcn_mfma_f32_16x16x32_bf16(pa0, bv0, o[c], 0, 0, 0);
      o[c] = __builtin_amdgcn_mfma_f32_16x16x32_bf16(pa1, bv1, o[c], 0, 0, 0);
    }
  }

  // ---- epilogue: normalize, store bf16 attn [B*T, N*H] ----
  #pragma unroll
  for (int r = 0; r < 4; r++){
    const float inv = 1.f / l_run[r];
    const int t = trow[r];
    #pragma unroll
    for (int c = 0; c < 4; c++)
      attn_out[(size_t)(b * TT + t) * 1024 + n * 64 + c * 16 + lcol] = f2bf(o[c][r] * inv);
  }
}

// ---------------- launcher ----------------
extern "C" void kernel_launch(void* const* d_in, const int* in_sizes, int n_in,
                              void* d_out, int out_size, void* d_ws, size_t ws_size,
                              hipStream_t stream){
  const float* x      = (const float*)d_in[0];
  const float* rel    = (const float*)d_in[1];
  const float* memory = (const float*)d_in[2];
  const int*   episode_idx = (const int*)d_in[3];
  const int*   dones  = (const int*)d_in[4];
  const float* Wq  = (const float*)d_in[5];
  const float* Wk  = (const float*)d_in[6];
  const float* Wv  = (const float*)d_in[7];
  const float* Wr  = (const float*)d_in[8];
  const float* u   = (const float*)d_in[9];
  const float* v   = (const float*)d_in[10];
  const float* Wout  = (const float*)d_in[11];
  const float* b_out = (const float*)d_in[12];
  float* out = (float*)d_out;

  char* ws = (char*)d_ws;
  size_t off = 0;
  auto alloc = [&](size_t bytes) -> char* {
    char* p = ws + off;
    off += (bytes + 255) & ~(size_t)255;
    return p;
  };
  short* kv_bf  = (short*)alloc((size_t)NB * SS * FF * 2);
  short* rel_bf = (short*)alloc((size_t)SS * FF * 2);
  short* WqT    = (short*)alloc((size_t)FF * 1024 * 2);
  short* WkT    = (short*)alloc((size_t)FF * 1024 * 2);
  short* WvT    = (short*)alloc((size_t)FF * 1024 * 2);
  short* WrT    = (short*)alloc((size_t)FF * 1024 * 2);
  short* WoT    = (short*)alloc((size_t)FF * 1024 * 2);
  short* qbuf   = (short*)alloc((size_t)NB * TT * 1024 * 2);
  short* kbf    = (short*)alloc((size_t)NB * SS * 1024 * 2);
  short* vTb    = (short*)alloc((size_t)NB * SS * 1024 * 2);
  short* rbf    = (short*)alloc((size_t)SS * 1024 * 2);
  int*   ki     = (int*)  alloc((size_t)NB * SS * 4);
  int2*  ranges = (int2*) alloc((size_t)NB * 64 * 8);
  float* ukT    = (float*)alloc((size_t)NB * NHD * SS * 4);
  float* vrT    = (float*)alloc((size_t)NHD * SS * 4);
  short* attn   = (short*)alloc((size_t)NB * TT * 1024 * 2);
  (void)ws_size; (void)in_sizes; (void)n_in; (void)out_size;

  // pack (fused kv + rel cast)
  const int n4 = NB*SS*FF/4 + SS*FF/4;
  build_inputs<<<(n4 + 255)/256, 256, 0, stream>>>(memory, x, rel, kv_bf, rel_bf);
  dim3 tb(32, 8), tg5(32, 32, 5);
  transpose_cast5<<<tg5, tb, 0, stream>>>(Wq, Wk, Wv, Wr, Wout, WqT, WkT, WvT, WrT, WoT);
  scan_kernel<<<NB, TT, 0, stream>>>(episode_idx, dones, ki, ranges);

  // fused projections, 128x64 tiles (R9 config) + dead K/V row-tile skip
  proj_gemm<<<dim3(32, 16, 4), 256, 0, stream>>>(kv_bf, rel_bf,
                                                 WkT, WvT, WqT, WrT,
                                                 kbf, vTb, qbuf, rbf, ranges);

  // u·k / v·r column-bias tables
  bias_tables<<<(NB*NHD*SS + NHD*SS + 255)/256, 256, 0, stream>>>(kbf, rbf, u, v, ukT, vrT);

  // attention: one wave per 16-row q-group, valid-interval sweep only
  attn_kernel<<<2048, 64, 0, stream>>>(qbuf, rbf, kbf, vTb, ki, ukT, vrT, ranges, attn);

  // output projection
  out_gemm<<<dim3(16, 16), 256, 0, stream>>>(attn, WoT, b_out, out);
}